// Round 9
// baseline (1349.321 us; speedup 1.0000x reference)
//
#include <hip/hip_runtime.h>

// ============================================================================
// SignLLM forward, fp32. B=4, T=32 -> nc=16 clips, D=512.
// Output: d_out[0..31] = widx (4,8) as float, d_out[32] = total loss.
// R9: conv2/conv3 remapped to 1x4-consecutive-col threads (bank-exact:
// (19p+4c)%32 / (3p+4c)%32 = 2 lanes/bank = free) + staging addr hoist.
// conv1 restructured: 1024 blocks, 2x2px x 16oc per thread, patch loaded
// once per ic (was 4x), deterministic per-(b,rq) stats partials.
// Zero atomics anywhere (tripwire-proven determinism).
// ============================================================================

// ---- workspace layout (float offsets), peak ~12.62M floats = 50.5 MB ----
static const size_t OFF_X1P  = 0;         // (64,64,32,32)  4,194,304  [dead after conv2]
static const size_t OFF_Y2   = 4194304;   // (64,128,32,32) 8,388,608  -> ends 12,582,912
static const size_t OFF_X2P  = 0;         // (64,128,16,16) 2,097,152  [x1p dead]
static const size_t OFF_Y3   = 4194304;   // (64,256,16,16) 4,194,304  [y2 dead]
// tail block in [2097152, 4194304): x1p dead by the time these are written
static const size_t OFF_X3P  = 2097152;   // 262,144
static const size_t OFF_Y4   = 2359296;   // 262,144
static const size_t OFF_X4   = 2621440;   // 262,144
static const size_t OFF_FEAT = 2883584;   // (64,512) 32,768
static const size_t OFF_QUANT= 2916352;   // 32,768
static const size_t OFF_GI1  = 2949120;   // (64,1536) 98,304 (rows b*16+t)
static const size_t OFF_GI2  = 3047424;   // 98,304
static const size_t OFF_H1   = 3145728;   // (64,512) rows b*16+t
static const size_t OFF_H2   = 3178496;   // 32,768
static const size_t OFF_WEMB = 3211264;   // (32,512) 16,384
static const size_t OFF_CTX  = 3227648;   // 2,048
static const size_t OFF_HH1  = 3229696;   // 2,048
static const size_t OFF_HH2  = 3231744;   // 4,096
static const size_t OFF_LOG  = 3235840;   // 12,000 -> ends 3,247,840
static const size_t OFF_PP   = 3247840;   // proj partials (8,64,512) 262,144 -> ends 3,509,984
// long-lived block PAST y2's end (12,582,912):
static const size_t OFF_SC    = 12582912; // 4,096
static const size_t OFF_SH    = 12587008; // 4,096
static const size_t OFF_ACCP  = 12591104; // 32,768: conv1 stats (s:16384, q:16384)
static const size_t OFF_COMMIT= 12623872; // 64
static const size_t OFF_CTXA  = 12623936; // 120
static const size_t OFF_ALIGNA= 12624056; // 32 -> ends 12,624,088

// ============================================================================
// conv1 (IC=3, 64x64, pad 1, mid temporal slice).
// Block = (ocg 0..3 [16 oc], rq 0..3 [16-row slab], n 0..63). 256 thr:
// rp = tid>>5 (0..7 row-pairs), cq = tid&31 (col-pairs). Thread = 2x2 px,
// ALL 16 oc (acc[4][16]). Patch loaded ONCE per ic. LDS: 3 x 18 x 66 slab.
// ============================================================================
__global__ __launch_bounds__(256) void k_conv1_stats3(
        const float* __restrict__ videos, const float* __restrict__ w1,
        const float* __restrict__ b1, float* __restrict__ accP) {
    __shared__ float sP[3 * 18 * 66];      // 3564
    __shared__ float wsm[3 * 9 * 16];      // 432
    __shared__ float sRed[4][16], qRed[4][16];
    int oc0 = blockIdx.x * 16, rq = blockIdx.y, n = blockIdx.z;
    int c = n >> 2, b = n & 3;
    int tid = threadIdx.x;
    int rp = tid >> 5, cq = tid & 31;
    for (int e = tid; e < 3564; e += 256) {
        int ic = e / 1188, rem = e % 1188;
        int r = rem / 66, col = rem % 66;
        int gr = rq * 16 - 1 + r, gc = col - 1;
        float v = 0.f;
        if (gr >= 0 && gr < 64 && gc >= 0 && gc < 64)
            v = videos[((size_t)(b * 3 + ic) * 32 + 2 * c) * 4096 + gr * 64 + gc];
        sP[e] = v;
    }
    for (int e = tid; e < 432; e += 256) {
        int ic = e / 144, rem = e % 144, k = rem / 16, j = rem % 16;
        wsm[e] = w1[((size_t)((oc0 + j) * 3 + ic) * 3 + 1) * 9 + k];
    }
    __syncthreads();
    float acc[4][16];
#pragma unroll
    for (int p = 0; p < 4; ++p)
#pragma unroll
        for (int j = 0; j < 16; ++j) acc[p][j] = 0.f;
#pragma unroll
    for (int ic = 0; ic < 3; ++ic) {
        const float* base = &sP[ic * 1188 + (2 * rp) * 66 + 2 * cq];
        float patch[4][4];
#pragma unroll
        for (int r = 0; r < 4; ++r)
#pragma unroll
            for (int q = 0; q < 4; ++q) patch[r][q] = base[r * 66 + q];
#pragma unroll
        for (int k = 0; k < 9; ++k) {
            int kr = k / 3, kc = k % 3;
            float4 w0 = *(const float4*)&wsm[(ic * 9 + k) * 16 + 0];
            float4 w1v = *(const float4*)&wsm[(ic * 9 + k) * 16 + 4];
            float4 w2 = *(const float4*)&wsm[(ic * 9 + k) * 16 + 8];
            float4 w3 = *(const float4*)&wsm[(ic * 9 + k) * 16 + 12];
#pragma unroll
            for (int p = 0; p < 4; ++p) {
                float vv = patch[(p >> 1) + kr][(p & 1) + kc];
                acc[p][0]  += vv * w0.x; acc[p][1]  += vv * w0.y;
                acc[p][2]  += vv * w0.z; acc[p][3]  += vv * w0.w;
                acc[p][4]  += vv * w1v.x; acc[p][5]  += vv * w1v.y;
                acc[p][6]  += vv * w1v.z; acc[p][7]  += vv * w1v.w;
                acc[p][8]  += vv * w2.x; acc[p][9]  += vv * w2.y;
                acc[p][10] += vv * w2.z; acc[p][11] += vv * w2.w;
                acc[p][12] += vv * w3.x; acc[p][13] += vv * w3.y;
                acc[p][14] += vv * w3.z; acc[p][15] += vv * w3.w;
            }
        }
    }
    int lane = tid & 63, wave = tid >> 6;
#pragma unroll
    for (int j = 0; j < 16; ++j) {
        float bj = b1[oc0 + j];
        float s = 0.f, q = 0.f;
#pragma unroll
        for (int p = 0; p < 4; ++p) {
            float a = acc[p][j] + bj;
            s += a; q += a * a;
        }
#pragma unroll
        for (int m = 1; m < 64; m <<= 1) {
            s += __shfl_xor(s, m);
            q += __shfl_xor(q, m);
        }
        if (lane == 0) { sRed[wave][j] = s; qRed[wave][j] = q; }
    }
    __syncthreads();
    if (tid < 16) {  // j = tid
        float s = ((sRed[0][tid] + sRed[1][tid]) + (sRed[2][tid] + sRed[3][tid]));
        float q = ((qRed[0][tid] + qRed[1][tid]) + (qRed[2][tid] + qRed[3][tid]));
        int oc = oc0 + tid;
        size_t slot = (((size_t)(c * 64 + oc)) * 4 + b) * 4 + rq;
        accP[slot] = s;
        accP[16384 + slot] = q;
    }
}

__global__ void k_conv1_fin(const float* __restrict__ accP, const float* __restrict__ g1,
                            const float* __restrict__ be1, float* __restrict__ sc,
                            float* __restrict__ sh) {
    int e = blockIdx.x * 256 + threadIdx.x;
    if (e >= 1024) return;
    int oc = e & 63;
    const float* ps = accP + (size_t)e * 16;
    const float* pq = accP + 16384 + (size_t)e * 16;
    float s = 0.f, q = 0.f;
#pragma unroll
    for (int i = 0; i < 16; ++i) { s += ps[i]; q += pq[i]; }
    float m = s * (1.f / 16384.f);
    float var = q * (1.f / 16384.f) - m * m;
    float sf = g1[oc] * rsqrtf(var + 1e-5f);
    sc[e] = sf;
    sh[e] = be1[oc] - m * sf;
}

__global__ __launch_bounds__(256) void k_conv1_apply3(
        const float* __restrict__ videos, const float* __restrict__ w1,
        const float* __restrict__ b1, const float* __restrict__ sc,
        const float* __restrict__ sh, float* __restrict__ x1p) {
    __shared__ float sP[3 * 18 * 66];
    __shared__ float wsm[3 * 9 * 16];
    int oc0 = blockIdx.x * 16, rq = blockIdx.y, n = blockIdx.z;
    int c = n >> 2, b = n & 3;
    int tid = threadIdx.x;
    int rp = tid >> 5, cq = tid & 31;
    for (int e = tid; e < 3564; e += 256) {
        int ic = e / 1188, rem = e % 1188;
        int r = rem / 66, col = rem % 66;
        int gr = rq * 16 - 1 + r, gc = col - 1;
        float v = 0.f;
        if (gr >= 0 && gr < 64 && gc >= 0 && gc < 64)
            v = videos[((size_t)(b * 3 + ic) * 32 + 2 * c) * 4096 + gr * 64 + gc];
        sP[e] = v;
    }
    for (int e = tid; e < 432; e += 256) {
        int ic = e / 144, rem = e % 144, k = rem / 16, j = rem % 16;
        wsm[e] = w1[((size_t)((oc0 + j) * 3 + ic) * 3 + 1) * 9 + k];
    }
    __syncthreads();
    float acc[4][16];
#pragma unroll
    for (int p = 0; p < 4; ++p)
#pragma unroll
        for (int j = 0; j < 16; ++j) acc[p][j] = 0.f;
#pragma unroll
    for (int ic = 0; ic < 3; ++ic) {
        const float* base = &sP[ic * 1188 + (2 * rp) * 66 + 2 * cq];
        float patch[4][4];
#pragma unroll
        for (int r = 0; r < 4; ++r)
#pragma unroll
            for (int q = 0; q < 4; ++q) patch[r][q] = base[r * 66 + q];
#pragma unroll
        for (int k = 0; k < 9; ++k) {
            int kr = k / 3, kc = k % 3;
            float4 w0 = *(const float4*)&wsm[(ic * 9 + k) * 16 + 0];
            float4 w1v = *(const float4*)&wsm[(ic * 9 + k) * 16 + 4];
            float4 w2 = *(const float4*)&wsm[(ic * 9 + k) * 16 + 8];
            float4 w3 = *(const float4*)&wsm[(ic * 9 + k) * 16 + 12];
#pragma unroll
            for (int p = 0; p < 4; ++p) {
                float vv = patch[(p >> 1) + kr][(p & 1) + kc];
                acc[p][0]  += vv * w0.x; acc[p][1]  += vv * w0.y;
                acc[p][2]  += vv * w0.z; acc[p][3]  += vv * w0.w;
                acc[p][4]  += vv * w1v.x; acc[p][5]  += vv * w1v.y;
                acc[p][6]  += vv * w1v.z; acc[p][7]  += vv * w1v.w;
                acc[p][8]  += vv * w2.x; acc[p][9]  += vv * w2.y;
                acc[p][10] += vv * w2.z; acc[p][11] += vv * w2.w;
                acc[p][12] += vv * w3.x; acc[p][13] += vv * w3.y;
                acc[p][14] += vv * w3.z; acc[p][15] += vv * w3.w;
            }
        }
    }
#pragma unroll
    for (int j = 0; j < 16; ++j) {
        int oc = oc0 + j;
        float bj = b1[oc];
        float scj = sc[c * 64 + oc], shj = sh[c * 64 + oc];
        float m = -1e30f;
#pragma unroll
        for (int p = 0; p < 4; ++p) m = fmaxf(m, (acc[p][j] + bj) * scj + shj);
        // pooled px: row rq*8+rp, col cq
        x1p[((size_t)n * 64 + oc) * 1024 + (rq * 8 + rp) * 32 + cq] = fmaxf(m, 0.f);
    }
}

// ============================================================================
// conv2: IC=64, 32x32, OC=128. Block = 1 clip x 8-row slab x 16 oc.
// grid (8 ocg, 4 slab, 64 n) = 2048 blocks. Thread = 4 oc x (1x4 consecutive
// cols): prow = pxq>>3, pc = pxq&7 -> cols 4pc. Banks (3*prow+4*pc)%32 =
// exactly 2/bank (free). Staging offsets hoisted out of the ic0 loop.
// ============================================================================
__global__ __launch_bounds__(256) void k_conv2(
        const float* __restrict__ in, const float* __restrict__ wt,
        const float* __restrict__ bias, float* __restrict__ out) {
    __shared__ float sIn[8 * 10 * 35];   // 2800
    __shared__ float sW[8 * 144];        // 1152
    int oc0 = blockIdx.x * 16, r0 = blockIdx.y * 8, n = blockIdx.z;
    int tid = threadIdx.x;
    int ocq = tid >> 6, pxq = tid & 63;
    int prow = pxq >> 3, pc = pxq & 7;   // px row r0+prow, cols 4pc..4pc+3
    const float* inN = in + (size_t)n * 65536;
    // hoisted staging offsets
    int inOff[11]; bool inOk[11];
#pragma unroll
    for (int i = 0; i < 11; ++i) {
        int e = tid + i * 256;
        inOk[i] = false; inOff[i] = 0;
        if (e < 2800) {
            int ch = e / 350, rem = e % 350;
            int r = rem / 35, col = rem % 35;
            int gr = r0 - 1 + r, gc = col - 1;
            inOk[i] = (gr >= 0 && gr < 32 && gc >= 0 && gc < 32);
            inOff[i] = ch * 1024 + gr * 32 + gc;
        }
    }
    size_t wOff[5];
#pragma unroll
    for (int i = 0; i < 5; ++i) {
        int e = tid + i * 256;
        wOff[i] = 0;
        if (e < 1152) {
            int c = e / 144, r1 = e % 144, k = r1 / 16, j = r1 % 16;
            wOff[i] = (size_t)(oc0 + j) * 1728 + c * 27 + 9 + k;
        }
    }
    float acc[4][4];
#pragma unroll
    for (int j = 0; j < 4; ++j)
#pragma unroll
        for (int p = 0; p < 4; ++p) acc[j][p] = 0.f;

    for (int ic0 = 0; ic0 < 64; ic0 += 8) {
        __syncthreads();
#pragma unroll
        for (int i = 0; i < 11; ++i) {
            int e = tid + i * 256;
            if (e < 2800) sIn[e] = inOk[i] ? inN[(size_t)ic0 * 1024 + inOff[i]] : 0.f;
        }
#pragma unroll
        for (int i = 0; i < 5; ++i) {
            int e = tid + i * 256;
            if (e < 1152) sW[e] = wt[wOff[i] + (size_t)ic0 * 27];
        }
        __syncthreads();
        for (int c = 0; c < 8; ++c) {
            const float* base = &sIn[c * 350 + prow * 35 + 4 * pc];
            float patch[3][6];
#pragma unroll
            for (int r = 0; r < 3; ++r)
#pragma unroll
                for (int q = 0; q < 6; ++q) patch[r][q] = base[r * 35 + q];
#pragma unroll
            for (int k = 0; k < 9; ++k) {
                int kr = k / 3, kc = k % 3;
                float4 w4 = *(const float4*)&sW[c * 144 + k * 16 + ocq * 4];  // wave-uniform
#pragma unroll
                for (int i = 0; i < 4; ++i) {
                    float vv = patch[kr][kc + i];
                    acc[0][i] += vv * w4.x; acc[1][i] += vv * w4.y;
                    acc[2][i] += vv * w4.z; acc[3][i] += vv * w4.w;
                }
            }
        }
    }
#pragma unroll
    for (int j = 0; j < 4; ++j) {
        int oc = oc0 + ocq * 4 + j;
        float bj = bias[oc];
        float4 o4 = make_float4(acc[j][0] + bj, acc[j][1] + bj, acc[j][2] + bj, acc[j][3] + bj);
        *(float4*)&out[((size_t)(n * 128 + oc) * 32 + r0 + prow) * 32 + 4 * pc] = o4;
    }
}

// ============================================================================
// conv3: IC=128, 16x16, OC=256. Block = 1 clip x full plane x 16 oc.
// grid (16 ocg, 64 n) = 1024 blocks. Thread = 4 oc x (1x4 consecutive cols):
// prow = pxq>>2, pc = pxq&3. Banks (19*prow+4*pc)%32 = 2/bank (free).
// ============================================================================
__global__ __launch_bounds__(256) void k_conv3k(
        const float* __restrict__ in, const float* __restrict__ wt,
        const float* __restrict__ bias, float* __restrict__ out) {
    __shared__ float sIn[8 * 18 * 19];   // 2736
    __shared__ float sW[8 * 144];
    int oc0 = blockIdx.x * 16, n = blockIdx.y;
    int tid = threadIdx.x;
    int ocq = tid >> 6, pxq = tid & 63;
    int prow = pxq >> 2, pc = pxq & 3;   // px row prow, cols 4pc..4pc+3
    const float* inN = in + (size_t)n * 32768;
    int inOff[11]; bool inOk[11];
#pragma unroll
    for (int i = 0; i < 11; ++i) {
        int e = tid + i * 256;
        inOk[i] = false; inOff[i] = 0;
        if (e < 2736) {
            int ch = e / 342, rem = e % 342;
            int r = rem / 19, cc = rem % 19;
            int gr = r - 1, gc = cc - 1;
            inOk[i] = (gr >= 0 && gr < 16 && gc >= 0 && gc < 16);
            inOff[i] = ch * 256 + gr * 16 + gc;
        }
    }
    size_t wOff[5];
#pragma unroll
    for (int i = 0; i < 5; ++i) {
        int e = tid + i * 256;
        wOff[i] = 0;
        if (e < 1152) {
            int c = e / 144, r1 = e % 144, k = r1 / 16, j = r1 % 16;
            wOff[i] = (size_t)(oc0 + j) * 3456 + c * 27 + 9 + k;
        }
    }
    float acc[4][4];
#pragma unroll
    for (int j = 0; j < 4; ++j)
#pragma unroll
        for (int p = 0; p < 4; ++p) acc[j][p] = 0.f;

    for (int ic0 = 0; ic0 < 128; ic0 += 8) {
        __syncthreads();
#pragma unroll
        for (int i = 0; i < 11; ++i) {
            int e = tid + i * 256;
            if (e < 2736) sIn[e] = inOk[i] ? inN[(size_t)ic0 * 256 + inOff[i]] : 0.f;
        }
#pragma unroll
        for (int i = 0; i < 5; ++i) {
            int e = tid + i * 256;
            if (e < 1152) sW[e] = wt[wOff[i] + (size_t)ic0 * 27];
        }
        __syncthreads();
        for (int c = 0; c < 8; ++c) {
            const float* base = &sIn[c * 342 + prow * 19 + 4 * pc];
            float patch[3][6];
#pragma unroll
            for (int r = 0; r < 3; ++r)
#pragma unroll
                for (int q = 0; q < 6; ++q) patch[r][q] = base[r * 19 + q];
#pragma unroll
            for (int k = 0; k < 9; ++k) {
                int kr = k / 3, kc = k % 3;
                float4 w4 = *(const float4*)&sW[c * 144 + k * 16 + ocq * 4];  // wave-uniform
#pragma unroll
                for (int i = 0; i < 4; ++i) {
                    float vv = patch[kr][kc + i];
                    acc[0][i] += vv * w4.x; acc[1][i] += vv * w4.y;
                    acc[2][i] += vv * w4.z; acc[3][i] += vv * w4.w;
                }
            }
        }
    }
#pragma unroll
    for (int j = 0; j < 4; ++j) {
        int oc = oc0 + ocq * 4 + j;
        float bj = bias[oc];
        float4 o4 = make_float4(acc[j][0] + bj, acc[j][1] + bj, acc[j][2] + bj, acc[j][3] + bj);
        *(float4*)&out[((size_t)(n * 256 + oc) * 16 + prow) * 16 + 4 * pc] = o4;
    }
}

// per-(clip,channel) BN stats
__global__ void k_bn_stats(const float* __restrict__ buf, const float* __restrict__ g,
                           const float* __restrict__ be, float* __restrict__ scale,
                           float* __restrict__ shift, int C, int HW) {
    int c = blockIdx.x, ch = blockIdx.y, tid = threadIdx.x;
    float s = 0.f, s2 = 0.f;
    for (int b = 0; b < 4; ++b) {
        const float* p = buf + ((size_t)(c * 4 + b) * C + ch) * HW;
        for (int i = tid; i < HW; i += 256) { float v = p[i]; s += v; s2 += v * v; }
    }
    __shared__ float rs[256], rq[256];
    rs[tid] = s; rq[tid] = s2; __syncthreads();
    for (int k = 128; k > 0; k >>= 1) {
        if (tid < k) { rs[tid] += rs[tid + k]; rq[tid] += rq[tid + k]; }
        __syncthreads();
    }
    if (tid == 0) {
        float inv = 1.f / (float)(4 * HW);
        float m = rs[0] * inv, var = rq[0] * inv - m * m;
        float sc = g[ch] * rsqrtf(var + 1e-5f);
        scale[c * C + ch] = sc;
        shift[c * C + ch] = be[ch] - m * sc;
    }
}

__global__ void k_bn_apply_pool(const float* __restrict__ in, const float* __restrict__ scale,
                                const float* __restrict__ shift, float* __restrict__ out,
                                int C, int H, int W) {
    int OH = H >> 1, OW = W >> 1;
    size_t idx = (size_t)blockIdx.x * 256 + threadIdx.x;
    int ow = (int)(idx % OW);
    size_t r = idx / OW;
    int oh = (int)(r % OH); r /= OH;
    int ch = (int)(r % C);
    int n = (int)(r / C);
    int c = n >> 2;
    float sc = scale[c * C + ch], sh = shift[c * C + ch];
    const float* p = in + (((size_t)n * C + ch) * H + 2 * oh) * W + 2 * ow;
    float m = 0.f;
    m = fmaxf(m, p[0] * sc + sh);
    m = fmaxf(m, p[1] * sc + sh);
    m = fmaxf(m, p[W] * sc + sh);
    m = fmaxf(m, p[W + 1] * sc + sh);
    out[idx] = m;
}

// ---- post-conv3 chain ----
__global__ void k_bn_apply_avgpool4(const float* __restrict__ in, const float* __restrict__ scale,
                                    const float* __restrict__ shift, float* __restrict__ out) {
    size_t idx = (size_t)blockIdx.x * 256 + threadIdx.x;  // 262,144
    int j = (int)(idx & 3), i = (int)(idx >> 2) & 3;
    int ch = (int)(idx >> 4) & 255, n = (int)(idx >> 12);
    int c = n >> 2;
    float sc = scale[c * 256 + ch], sh = shift[c * 256 + ch];
    const float* p = in + (((size_t)n * 256 + ch) * 16 + i * 4) * 16 + j * 4;
    float s = 0.f;
#pragma unroll
    for (int r = 0; r < 4; ++r)
#pragma unroll
        for (int q = 0; q < 4; ++q) s += fmaxf(p[r * 16 + q] * sc + sh, 0.f);
    out[idx] = s * (1.f / 16.f);
}

__global__ void k_tconv(const float* __restrict__ x3p, const float* __restrict__ tw,
                        const float* __restrict__ tb, float* __restrict__ y4) {
    size_t idx = (size_t)blockIdx.x * 256 + threadIdx.x;  // 262,144
    int p = (int)(idx & 15), o = (int)(idx >> 4) & 255, n = (int)(idx >> 12);
    const float* xr = x3p + (size_t)n * 4096 + p;
    float a = tb[o];
    for (int i = 0; i < 256; ++i) a += xr[i * 16] * tw[((size_t)o * 256 + i) * 3 + 1];
    y4[idx] = a;
}

__global__ void k_bn_apply(const float* __restrict__ in, const float* __restrict__ scale,
                           const float* __restrict__ shift, float* __restrict__ out) {
    size_t idx = (size_t)blockIdx.x * 256 + threadIdx.x;  // 262,144
    int ch = (int)(idx >> 4) & 255, n = (int)(idx >> 12);
    int c = n >> 2;
    float sc = scale[c * 256 + ch], sh = shift[c * 256 + ch];
    out[idx] = fmaxf(in[idx] * sc + sh, 0.f);
}

// ============================================================================
// proj as deterministic split-K GEMM with row permutation in fin.
// ============================================================================
__global__ __launch_bounds__(256) void k_proj_part(
        const float* __restrict__ A, const float* __restrict__ B, float* __restrict__ PP) {
    __shared__ __align__(16) float As[64 * 68];
    __shared__ __align__(16) float Bs[64 * 68];
    int n0 = blockIdx.x * 64, ks = blockIdx.y;
    int tid = threadIdx.x, tm = tid >> 4, tn = tid & 15;
    float acc[4][4];
#pragma unroll
    for (int i = 0; i < 4; ++i)
#pragma unroll
        for (int j = 0; j < 4; ++j) acc[i][j] = 0.f;
    int kb = ks * 512;
    for (int k0 = kb; k0 < kb + 512; k0 += 64) {
        __syncthreads();
        for (int e = tid; e < 4096; e += 256) {
            int m = e >> 6, k = e & 63;
            As[k * 68 + m] = A[(size_t)m * 4096 + k0 + k];
            Bs[k * 68 + m] = B[(size_t)(n0 + m) * 4096 + k0 + k];
        }
        __syncthreads();
        for (int k = 0; k < 64; ++k) {
            float4 a4 = *(const float4*)&As[k * 68 + tm * 4];
            float4 b4 = *(const float4*)&Bs[k * 68 + tn * 4];
            acc[0][0] += a4.x * b4.x; acc[0][1] += a4.x * b4.y;
            acc[0][2] += a4.x * b4.z; acc[0][3] += a4.x * b4.w;
            acc[1][0] += a4.y * b4.x; acc[1][1] += a4.y * b4.y;
            acc[1][2] += a4.y * b4.z; acc[1][3] += a4.y * b4.w;
            acc[2][0] += a4.z * b4.x; acc[2][1] += a4.z * b4.y;
            acc[2][2] += a4.z * b4.z; acc[2][3] += a4.z * b4.w;
            acc[3][0] += a4.w * b4.x; acc[3][1] += a4.w * b4.y;
            acc[3][2] += a4.w * b4.z; acc[3][3] += a4.w * b4.w;
        }
    }
#pragma unroll
    for (int i = 0; i < 4; ++i)
#pragma unroll
        for (int j = 0; j < 4; ++j)
            PP[((size_t)(ks * 64 + tm * 4 + i)) * 512 + n0 + tn * 4 + j] = acc[i][j];
}

__global__ void k_proj_fin(const float* __restrict__ PP, const float* __restrict__ pb,
                           float* __restrict__ feat) {
    int e = blockIdx.x * 256 + threadIdx.x;  // 32768
    int n = e & 511;
    int m = e >> 9;               // x4 row (clip-major): m = c*4 + b
    float s = pb[n];
#pragma unroll
    for (int ks = 0; ks < 8; ++ks) s += PP[(size_t)ks * 32768 + e];
    int c = m >> 2, b = m & 3;
    int ro = b * 16 + c;          // feat row (batch-major)
    feat[(size_t)ro * 512 + n] = s;
}

// VQ argmin; min distance -> commitArr[row] (deterministic)
__global__ void k_vq(const float* __restrict__ feat, const float* __restrict__ cb,
                     float* __restrict__ quant, float* __restrict__ commitArr) {
    int row = blockIdx.x, tid = threadIdx.x;
    __shared__ float f[512];
    for (int k = tid; k < 512; k += 256) f[k] = feat[(size_t)row * 512 + k];
    __syncthreads();
    float best = 3.4e38f; int bidx = 0;
    for (int j = tid; j < 1024; j += 256) {
        const float* c = cb + (size_t)j * 512;
        float d2 = 0.f;
        for (int k = 0; k < 512; ++k) { float t = f[k] - c[k]; d2 += t * t; }
        if (d2 < best) { best = d2; bidx = j; }
    }
    __shared__ float rd[256]; __shared__ int ri[256];
    rd[tid] = best; ri[tid] = bidx; __syncthreads();
    for (int k = 128; k > 0; k >>= 1) {
        if (tid < k) {
            float od = rd[tid + k]; int oi = ri[tid + k];
            if (od < rd[tid] || (od == rd[tid] && oi < ri[tid])) { rd[tid] = od; ri[tid] = oi; }
        }
        __syncthreads();
    }
    __shared__ int wsel;
    if (tid == 0) { wsel = ri[0]; commitArr[row] = rd[0]; }
    __syncthreads();
    const float* c = cb + (size_t)wsel * 512;
    for (int k = tid; k < 512; k += 256) quant[(size_t)row * 512 + k] = c[k];
}

// gi = X @ w_ih.T + b_ih, rows (b, t) t=0..14; X and gi rows at stride-16 (b*16+t)
__global__ void k_gru_gi(const float* __restrict__ x, const float* __restrict__ wih,
                         const float* __restrict__ bih, float* __restrict__ gi) {
    int r = blockIdx.x;  // 0..59
    int b = r / 15, t = r % 15;
    const float* xr = x + ((size_t)(b * 16 + t)) * 512;
    __shared__ float xsRow[512];
    for (int k = threadIdx.x; k < 512; k += 256) xsRow[k] = xr[k];
    __syncthreads();
    const float4* xp = (const float4*)xsRow;
    for (int d = threadIdx.x; d < 1536; d += 256) {
        const float4* wr = (const float4*)(wih + (size_t)d * 512);
        float a0 = 0.f, a1 = 0.f, a2 = 0.f, a3 = 0.f;
        for (int i = 0; i < 128; i += 4) {
            float4 w0 = wr[i], w1 = wr[i + 1], w2 = wr[i + 2], w3 = wr[i + 3];
            float4 x0 = xp[i], x1 = xp[i + 1], x2 = xp[i + 2], x3 = xp[i + 3];
            a0 += w0.x * x0.x + w0.y * x0.y + w0.z * x0.z + w0.w * x0.w;
            a1 += w1.x * x1.x + w1.y * x1.y + w1.z * x1.z + w1.w * x1.w;
            a2 += w2.x * x2.x + w2.y * x2.y + w2.z * x2.z + w2.w * x2.w;
            a3 += w3.x * x3.x + w3.y * x3.y + w3.z * x3.z + w3.w * x3.w;
        }
        gi[((size_t)(b * 16 + t)) * 1536 + d] = (a0 + a1) + (a2 + a3) + bih[d];
    }
}

// One GRU step: grid 128 (4 h-dims each), wave = one h-dim, float4 rows.
__global__ void k_gru_step2(const float* __restrict__ gi, const float* __restrict__ whh,
                            const float* __restrict__ bhh, float* __restrict__ hseq, int t) {
    int wv = threadIdx.x >> 6, lane = threadIdx.x & 63;
    int d = blockIdx.x * 4 + wv;
    const float4* w0p = (const float4*)(whh + (size_t)d * 512);
    const float4* w1p = (const float4*)(whh + (size_t)(512 + d) * 512);
    const float4* w2p = (const float4*)(whh + (size_t)(1024 + d) * 512);
    float4 w0a = w0p[lane * 2], w0b = w0p[lane * 2 + 1];
    float4 w1a = w1p[lane * 2], w1b = w1p[lane * 2 + 1];
    float4 w2a = w2p[lane * 2], w2b = w2p[lane * 2 + 1];
    float bh0 = bhh[d], bh1 = bhh[512 + d], bh2 = bhh[1024 + d];
    for (int b = 0; b < 4; ++b) {
        float4 ha = make_float4(0, 0, 0, 0), hb = ha;
        float hpd = 0.f;
        if (t > 0) {
            const float4* hp = (const float4*)(hseq + (size_t)(b * 16 + t - 1) * 512);
            ha = hp[lane * 2]; hb = hp[lane * 2 + 1];
            hpd = hseq[(size_t)(b * 16 + t - 1) * 512 + d];
        }
        float s0 = w0a.x * ha.x + w0a.y * ha.y + w0a.z * ha.z + w0a.w * ha.w
                 + w0b.x * hb.x + w0b.y * hb.y + w0b.z * hb.z + w0b.w * hb.w;
        float s1 = w1a.x * ha.x + w1a.y * ha.y + w1a.z * ha.z + w1a.w * ha.w
                 + w1b.x * hb.x + w1b.y * hb.y + w1b.z * hb.z + w1b.w * hb.w;
        float s2 = w2a.x * ha.x + w2a.y * ha.y + w2a.z * ha.z + w2a.w * ha.w
                 + w2b.x * hb.x + w2b.y * hb.y + w2b.z * hb.z + w2b.w * hb.w;
#pragma unroll
        for (int m = 1; m < 64; m <<= 1) {
            s0 += __shfl_xor(s0, m);
            s1 += __shfl_xor(s1, m);
            s2 += __shfl_xor(s2, m);
        }
        const float* gr = gi + (size_t)(b * 16 + t) * 1536;
        float rr = 1.f / (1.f + expf(-(gr[d] + s0 + bh0)));
        float zz = 1.f / (1.f + expf(-(gr[512 + d] + s1 + bh1)));
        float nn = tanhf(gr[1024 + d] + rr * (s2 + bh2));
        if (lane == 0)
            hseq[(size_t)(b * 16 + t) * 512 + d] = (1.f - zz) * nn + zz * hpd;
    }
}

// ctx loss partials -> ctxArr[block] (deterministic)
__global__ void k_ctx_loss(const float* __restrict__ h2, const float* __restrict__ feat,
                           float* __restrict__ ctxArr) {
    int tid = threadIdx.x;
    size_t idx = (size_t)blockIdx.x * 256 + tid;  // 30720
    int d = (int)(idx & 511);
    int rt = (int)(idx >> 9);
    int t = rt % 15, b = rt / 15;
    float diff = h2[(size_t)(b * 16 + t) * 512 + d] - feat[(size_t)(b * 16 + t + 1) * 512 + d];
    float v = diff * diff;
#pragma unroll
    for (int m = 1; m < 64; m <<= 1) v += __shfl_xor(v, m);
    __shared__ float ws[4];
    if ((tid & 63) == 0) ws[tid >> 6] = v;
    __syncthreads();
    if (tid == 0) ctxArr[blockIdx.x] = ((ws[0] + ws[1]) + (ws[2] + ws[3]));
}

__global__ void k_word_vq(const float* __restrict__ quant, const float* __restrict__ wcb,
                          float* __restrict__ wemb, float* __restrict__ out_widx) {
    int row = blockIdx.x;  // b*8+wi
    int b = row >> 3, wi = row & 7;
    int tid = threadIdx.x;
    __shared__ float f[512];
    for (int k = tid; k < 512; k += 256)
        f[k] = 0.5f * (quant[(size_t)(b * 16 + 2 * wi) * 512 + k] +
                       quant[(size_t)(b * 16 + 2 * wi + 1) * 512 + k]);
    __syncthreads();
    const float* cp = wcb + (size_t)tid * 512;
    float d2 = 0.f;
    for (int k = 0; k < 512; ++k) { float t = f[k] - cp[k]; d2 += t * t; }
    __shared__ float rd[256]; __shared__ int ri[256];
    rd[tid] = d2; ri[tid] = tid; __syncthreads();
    for (int k = 128; k > 0; k >>= 1) {
        if (tid < k) {
            float od = rd[tid + k]; int oi = ri[tid + k];
            if (od < rd[tid] || (od == rd[tid] && oi < ri[tid])) { rd[tid] = od; ri[tid] = oi; }
        }
        __syncthreads();
    }
    __shared__ int wsel;
    if (tid == 0) { wsel = ri[0]; out_widx[row] = (float)ri[0]; }
    __syncthreads();
    const float* cb = wcb + (size_t)wsel * 512;
    for (int k = tid; k < 512; k += 256) wemb[(size_t)row * 512 + k] = cb[k];
}

// alignment partials -> alignArr[row] (deterministic)
__global__ void k_align(const float* __restrict__ wemb, const float* __restrict__ aw,
                        const float* __restrict__ ab, float* __restrict__ alignArr) {
    int row = blockIdx.x, tid = threadIdx.x;
    __shared__ float e[512];
    for (int k = tid; k < 512; k += 256) e[k] = wemb[(size_t)row * 512 + k];
    __syncthreads();
    float local = 0.f;
    for (int d = tid; d < 512; d += 256) {
        const float* wr = aw + (size_t)d * 512;
        float a = ab[d] - e[d];
        for (int k = 0; k < 512; ++k) a += e[k] * wr[k];
        local += a * a;
    }
    __shared__ float rs[256];
    rs[tid] = local; __syncthreads();
    for (int k = 128; k > 0; k >>= 1) { if (tid < k) rs[tid] += rs[tid + k]; __syncthreads(); }
    if (tid == 0) alignArr[row] = rs[0];
}

__global__ void k_ctx(const float* __restrict__ wemb, float* __restrict__ ctx) {
    int e = blockIdx.x * 256 + threadIdx.x;  // 2048
    int b = e >> 9, d = e & 511;
    float s = 0.f;
#pragma unroll
    for (int wi = 0; wi < 8; ++wi) s += wemb[(size_t)(b * 8 + wi) * 512 + d];
    ctx[e] = s * 0.125f;
}

// small-M (M=4) GEMV: C[4,N] = A[4,K] @ B[N,K]^T + bias, optional relu.
__global__ void k_smallM(const float* __restrict__ A, const float* __restrict__ B,
                         const float* __restrict__ bias, float* __restrict__ C,
                         int N, int K, int relu) {
    __shared__ float xs[4096];
    int tid = threadIdx.x;
    for (int e = tid; e < 4 * K; e += 256) xs[e] = A[e];
    __syncthreads();
    int r = tid >> 4, kt = tid & 15;
    int n = blockIdx.x * 16 + r;
    float acc[4] = {0, 0, 0, 0};
    if (n < N) {
        int iters = K >> 6;
        for (int i = 0; i < iters; ++i) {
            int k = i * 64 + kt * 4;
            float4 w = *(const float4*)&B[(size_t)n * K + k];
#pragma unroll
            for (int b = 0; b < 4; ++b) {
                float4 x = *(const float4*)&xs[b * K + k];
                acc[b] += w.x * x.x + w.y * x.y + w.z * x.z + w.w * x.w;
            }
        }
    }
#pragma unroll
    for (int b = 0; b < 4; ++b) {
#pragma unroll
        for (int m = 1; m < 16; m <<= 1) acc[b] += __shfl_xor(acc[b], m);
    }
    if (kt == 0 && n < N) {
#pragma unroll
        for (int b = 0; b < 4; ++b) {
            float v = acc[b] + bias[n];
            if (relu) v = fmaxf(v, 0.f);
            C[(size_t)b * N + n] = v;
        }
    }
}

// log-softmax CE + deterministic fixed-order sum of all loss partials
__global__ void k_final(const float* __restrict__ logits, const int* __restrict__ tokens,
                        const float* __restrict__ commitArr, const float* __restrict__ ctxArr,
                        const float* __restrict__ alignArr, float* __restrict__ out_total) {
    int tid = threadIdx.x;
    __shared__ float rs[256];
    __shared__ float sM;
    float tr = 0.f;
    for (int b = 0; b < 4; ++b) {
        const float* lg = logits + (size_t)b * 3000;
        float m = -1e30f;
        for (int d = tid; d < 3000; d += 256) m = fmaxf(m, lg[d]);
        rs[tid] = m; __syncthreads();
        for (int k = 128; k > 0; k >>= 1) { if (tid < k) rs[tid] = fmaxf(rs[tid], rs[tid + k]); __syncthreads(); }
        if (tid == 0) sM = rs[0];
        __syncthreads();
        float M = sM;
        float s = 0.f;
        for (int d = tid; d < 3000; d += 256) s += expf(lg[d] - M);
        rs[tid] = s; __syncthreads();
        for (int k = 128; k > 0; k >>= 1) { if (tid < k) rs[tid] += rs[tid + k]; __syncthreads(); }
        if (tid == 0) {
            int t0 = tokens[b * 10];
            tr += -(lg[t0] - M - logf(rs[0]));
        }
        __syncthreads();
    }
    if (tid == 0) {
        float c0 = 0.f;
        for (int i = 0; i < 64; ++i) c0 += commitArr[i];
        float c1 = 0.f;
        for (int i = 0; i < 120; ++i) c1 += ctxArr[i];
        float c2 = 0.f;
        for (int i = 0; i < 32; ++i) c2 += alignArr[i];
        float total = 1.25f * c0 * (1.f / 32768.f)
                    + 0.1f  * c1 * (1.f / 30720.f)
                    + 0.1f  * c2 * (1.f / 16384.f)
                    + tr;
        *out_total = total;
    }
}

extern "C" void kernel_launch(void* const* d_in, const int* in_sizes, int n_in,
                              void* d_out, int out_size, void* d_ws, size_t ws_size,
                              hipStream_t stream) {
    (void)in_sizes; (void)n_in; (void)out_size; (void)ws_size;
    const float* videos   = (const float*)d_in[0];
    const float* conv1_w  = (const float*)d_in[1];
    const float* conv1_b  = (const float*)d_in[2];
    const float* bn1_g    = (const float*)d_in[3];
    const float* bn1_b    = (const float*)d_in[4];
    const float* conv2_w  = (const float*)d_in[5];
    const float* conv2_b  = (const float*)d_in[6];
    const float* bn2_g    = (const float*)d_in[7];
    const float* bn2_b    = (const float*)d_in[8];
    const float* conv3_w  = (const float*)d_in[9];
    const float* conv3_b  = (const float*)d_in[10];
    const float* bn3_g    = (const float*)d_in[11];
    const float* bn3_b    = (const float*)d_in[12];
    const float* tconv_w  = (const float*)d_in[13];
    const float* tconv_b  = (const float*)d_in[14];
    const float* bn4_g    = (const float*)d_in[15];
    const float* bn4_b    = (const float*)d_in[16];
    const float* proj_w   = (const float*)d_in[17];
    const float* proj_b   = (const float*)d_in[18];
    const float* codebook = (const float*)d_in[19];
    const float* word_cb  = (const float*)d_in[20];
    const float* align_w  = (const float*)d_in[21];
    const float* align_b  = (const float*)d_in[22];
    const float* gru_wih0 = (const float*)d_in[23];
    const float* gru_whh0 = (const float*)d_in[24];
    const float* gru_bih0 = (const float*)d_in[25];
    const float* gru_bhh0 = (const float*)d_in[26];
    const float* gru_wih1 = (const float*)d_in[27];
    const float* gru_whh1 = (const float*)d_in[28];
    const float* gru_bih1 = (const float*)d_in[29];
    const float* gru_bhh1 = (const float*)d_in[30];
    const float* dec1_w   = (const float*)d_in[31];
    const float* dec1_b   = (const float*)d_in[32];
    const float* dec2_w   = (const float*)d_in[33];
    const float* dec2_b   = (const float*)d_in[34];
    const float* dec3_w   = (const float*)d_in[35];
    const float* dec3_b   = (const float*)d_in[36];
    const int*   tokens   = (const int*)d_in[37];

    float* wsf    = (float*)d_ws;
    float* out    = (float*)d_out;
    float* x1p    = wsf + OFF_X1P;
    float* x2p    = wsf + OFF_X2P;
    float* y2     = wsf + OFF_Y2;
    float* y3     = wsf + OFF_Y3;
    float* x3p    = wsf + OFF_X3P;
    float* y4     = wsf + OFF_Y4;
    float* x4     = wsf + OFF_X4;
    float* feat   = wsf + OFF_FEAT;
    float* quant  = wsf + OFF_QUANT;
    float* gi1    = wsf + OFF_GI1;
    float* gi2    = wsf + OFF_GI2;
    float* h1     = wsf + OFF_H1;
    float* h2     = wsf + OFF_H2;
    float* wemb   = wsf + OFF_WEMB;
    float* ctx    = wsf + OFF_CTX;
    float* hh1    = wsf + OFF_HH1;
    float* hh2    = wsf + OFF_HH2;
    float* logit  = wsf + OFF_LOG;
    float* pp     = wsf + OFF_PP;
    float* sc     = wsf + OFF_SC;
    float* sh     = wsf + OFF_SH;
    float* accP   = wsf + OFF_ACCP;
    float* commitA= wsf + OFF_COMMIT;
    float* ctxA   = wsf + OFF_CTXA;
    float* alignA = wsf + OFF_ALIGNA;

    // conv1 + bn1 + pool
    k_conv1_stats3<<<dim3(4, 4, 64), 256, 0, stream>>>(videos, conv1_w, conv1_b, accP);
    k_conv1_fin<<<4, 256, 0, stream>>>(accP, bn1_g, bn1_b, sc, sh);
    k_conv1_apply3<<<dim3(4, 4, 64), 256, 0, stream>>>(videos, conv1_w, conv1_b, sc, sh, x1p);
    // conv2 + bn2 + pool
    k_conv2<<<dim3(8, 4, 64), 256, 0, stream>>>(x1p, conv2_w, conv2_b, y2);
    k_bn_stats<<<dim3(16, 128), 256, 0, stream>>>(y2, bn2_g, bn2_b, sc, sh, 128, 1024);
    k_bn_apply_pool<<<8192, 256, 0, stream>>>(y2, sc, sh, x2p, 128, 32, 32);
    // conv3 + bn3 + chain
    k_conv3k<<<dim3(16, 64), 256, 0, stream>>>(x2p, conv3_w, conv3_b, y3);
    k_bn_stats<<<dim3(16, 256), 256, 0, stream>>>(y3, bn3_g, bn3_b, sc, sh, 256, 256);
    k_bn_apply_avgpool4<<<1024, 256, 0, stream>>>(y3, sc, sh, x3p);
    k_tconv<<<1024, 256, 0, stream>>>(x3p, tconv_w, tconv_b, y4);
    k_bn_stats<<<dim3(16, 256), 256, 0, stream>>>(y4, bn4_g, bn4_b, sc, sh, 256, 16);
    k_bn_apply<<<1024, 256, 0, stream>>>(y4, sc, sh, x4);
    // projection (deterministic split-K GEMM, row permutation in fin)
    k_proj_part<<<dim3(8, 8), 256, 0, stream>>>(x4, proj_w, pp);
    k_proj_fin<<<128, 256, 0, stream>>>(pp, proj_b, feat);
    k_vq<<<64, 256, 0, stream>>>(feat, codebook, quant, commitA);
    // GRU layer 1
    k_gru_gi<<<60, 256, 0, stream>>>(quant, gru_wih0, gru_bih0, gi1);
    for (int t = 0; t < 15; ++t)
        k_gru_step2<<<128, 256, 0, stream>>>(gi1, gru_whh0, gru_bhh0, h1, t);
    // GRU layer 2
    k_gru_gi<<<60, 256, 0, stream>>>(h1, gru_wih1, gru_bih1, gi2);
    for (int t = 0; t < 15; ++t)
        k_gru_step2<<<128, 256, 0, stream>>>(gi2, gru_whh1, gru_bhh1, h2, t);
    k_ctx_loss<<<120, 256, 0, stream>>>(h2, feat, ctxA);
    // word VQ + alignment
    k_word_vq<<<32, 256, 0, stream>>>(quant, word_cb, wemb, out);
    k_align<<<32, 256, 0, stream>>>(wemb, align_w, align_b, alignA);
    // decoder
    k_ctx<<<8, 256, 0, stream>>>(wemb, ctx);
    k_smallM<<<32, 256, 0, stream>>>(ctx, dec1_w, dec1_b, hh1, 512, 512, 1);
    k_smallM<<<64, 256, 0, stream>>>(hh1, dec2_w, dec2_b, hh2, 1024, 512, 1);
    k_smallM<<<188, 256, 0, stream>>>(hh2, dec3_w, dec3_b, logit, 3000, 1024, 0);
    k_final<<<1, 256, 0, stream>>>(logit, tokens, commitA, ctxA, alignA, out + 32);
}

// Round 10
// 1216.889 us; speedup vs baseline: 1.1088x; 1.1088x over previous
//
#include <hip/hip_runtime.h>

// ============================================================================
// SignLLM forward, fp32. B=4, T=32 -> nc=16 clips, D=512.
// Output: d_out[0..31] = widx (4,8) as float, d_out[32] = total loss.
// R10: conv2/conv3 re-tiled to 4oc x 8px(2x4) per thread (288 FMA per 24 LDS
// reads per c-iter -> LDS pipe no longer CU-saturating). R9's VGPR-heavy
// offset hoisting reverted (occupancy 22.6% -> ~38%). conv1/rest = R9.
// Zero atomics anywhere (deterministic).
// ============================================================================

// ---- workspace layout (float offsets), peak ~12.62M floats = 50.5 MB ----
static const size_t OFF_X1P  = 0;         // (64,64,32,32)  4,194,304  [dead after conv2]
static const size_t OFF_Y2   = 4194304;   // (64,128,32,32) 8,388,608  -> ends 12,582,912
static const size_t OFF_X2P  = 0;         // (64,128,16,16) 2,097,152  [x1p dead]
static const size_t OFF_Y3   = 4194304;   // (64,256,16,16) 4,194,304  [y2 dead]
static const size_t OFF_X3P  = 2097152;   // 262,144
static const size_t OFF_Y4   = 2359296;   // 262,144
static const size_t OFF_X4   = 2621440;   // 262,144
static const size_t OFF_FEAT = 2883584;   // (64,512) 32,768
static const size_t OFF_QUANT= 2916352;   // 32,768
static const size_t OFF_GI1  = 2949120;   // (64,1536) 98,304 (rows b*16+t)
static const size_t OFF_GI2  = 3047424;   // 98,304
static const size_t OFF_H1   = 3145728;   // (64,512) rows b*16+t
static const size_t OFF_H2   = 3178496;   // 32,768
static const size_t OFF_WEMB = 3211264;   // (32,512) 16,384
static const size_t OFF_CTX  = 3227648;   // 2,048
static const size_t OFF_HH1  = 3229696;   // 2,048
static const size_t OFF_HH2  = 3231744;   // 4,096
static const size_t OFF_LOG  = 3235840;   // 12,000 -> ends 3,247,840
static const size_t OFF_PP   = 3247840;   // proj partials (8,64,512) 262,144
// long-lived block PAST y2's end (12,582,912):
static const size_t OFF_SC    = 12582912; // 4,096
static const size_t OFF_SH    = 12587008; // 4,096
static const size_t OFF_ACCP  = 12591104; // 32,768: conv1 stats (s:16384, q:16384)
static const size_t OFF_COMMIT= 12623872; // 64
static const size_t OFF_CTXA  = 12623936; // 120
static const size_t OFF_ALIGNA= 12624056; // 32

// ============================================================================
// conv1 (IC=3, 64x64, pad 1, mid temporal slice). Block = (ocg, rq, n),
// 256 thr = 2x2px x 16oc. Deterministic per-(c,oc,b,rq) stats partials.
// ============================================================================
__global__ __launch_bounds__(256) void k_conv1_stats3(
        const float* __restrict__ videos, const float* __restrict__ w1,
        const float* __restrict__ b1, float* __restrict__ accP) {
    __shared__ float sP[3 * 18 * 66];
    __shared__ float wsm[3 * 9 * 16];
    __shared__ float sRed[4][16], qRed[4][16];
    int oc0 = blockIdx.x * 16, rq = blockIdx.y, n = blockIdx.z;
    int c = n >> 2, b = n & 3;
    int tid = threadIdx.x;
    int rp = tid >> 5, cq = tid & 31;
    for (int e = tid; e < 3564; e += 256) {
        int ic = e / 1188, rem = e % 1188;
        int r = rem / 66, col = rem % 66;
        int gr = rq * 16 - 1 + r, gc = col - 1;
        float v = 0.f;
        if (gr >= 0 && gr < 64 && gc >= 0 && gc < 64)
            v = videos[((size_t)(b * 3 + ic) * 32 + 2 * c) * 4096 + gr * 64 + gc];
        sP[e] = v;
    }
    for (int e = tid; e < 432; e += 256) {
        int ic = e / 144, rem = e % 144, k = rem / 16, j = rem % 16;
        wsm[e] = w1[((size_t)((oc0 + j) * 3 + ic) * 3 + 1) * 9 + k];
    }
    __syncthreads();
    float acc[4][16];
#pragma unroll
    for (int p = 0; p < 4; ++p)
#pragma unroll
        for (int j = 0; j < 16; ++j) acc[p][j] = 0.f;
#pragma unroll
    for (int ic = 0; ic < 3; ++ic) {
        const float* base = &sP[ic * 1188 + (2 * rp) * 66 + 2 * cq];
        float patch[4][4];
#pragma unroll
        for (int r = 0; r < 4; ++r)
#pragma unroll
            for (int q = 0; q < 4; ++q) patch[r][q] = base[r * 66 + q];
#pragma unroll
        for (int k = 0; k < 9; ++k) {
            int kr = k / 3, kc = k % 3;
            float4 w0 = *(const float4*)&wsm[(ic * 9 + k) * 16 + 0];
            float4 w1v = *(const float4*)&wsm[(ic * 9 + k) * 16 + 4];
            float4 w2 = *(const float4*)&wsm[(ic * 9 + k) * 16 + 8];
            float4 w3 = *(const float4*)&wsm[(ic * 9 + k) * 16 + 12];
#pragma unroll
            for (int p = 0; p < 4; ++p) {
                float vv = patch[(p >> 1) + kr][(p & 1) + kc];
                acc[p][0]  += vv * w0.x; acc[p][1]  += vv * w0.y;
                acc[p][2]  += vv * w0.z; acc[p][3]  += vv * w0.w;
                acc[p][4]  += vv * w1v.x; acc[p][5]  += vv * w1v.y;
                acc[p][6]  += vv * w1v.z; acc[p][7]  += vv * w1v.w;
                acc[p][8]  += vv * w2.x; acc[p][9]  += vv * w2.y;
                acc[p][10] += vv * w2.z; acc[p][11] += vv * w2.w;
                acc[p][12] += vv * w3.x; acc[p][13] += vv * w3.y;
                acc[p][14] += vv * w3.z; acc[p][15] += vv * w3.w;
            }
        }
    }
    int lane = tid & 63, wave = tid >> 6;
#pragma unroll
    for (int j = 0; j < 16; ++j) {
        float bj = b1[oc0 + j];
        float s = 0.f, q = 0.f;
#pragma unroll
        for (int p = 0; p < 4; ++p) {
            float a = acc[p][j] + bj;
            s += a; q += a * a;
        }
#pragma unroll
        for (int m = 1; m < 64; m <<= 1) {
            s += __shfl_xor(s, m);
            q += __shfl_xor(q, m);
        }
        if (lane == 0) { sRed[wave][j] = s; qRed[wave][j] = q; }
    }
    __syncthreads();
    if (tid < 16) {
        float s = ((sRed[0][tid] + sRed[1][tid]) + (sRed[2][tid] + sRed[3][tid]));
        float q = ((qRed[0][tid] + qRed[1][tid]) + (qRed[2][tid] + qRed[3][tid]));
        int oc = oc0 + tid;
        size_t slot = (((size_t)(c * 64 + oc)) * 4 + b) * 4 + rq;
        accP[slot] = s;
        accP[16384 + slot] = q;
    }
}

__global__ void k_conv1_fin(const float* __restrict__ accP, const float* __restrict__ g1,
                            const float* __restrict__ be1, float* __restrict__ sc,
                            float* __restrict__ sh) {
    int e = blockIdx.x * 256 + threadIdx.x;
    if (e >= 1024) return;
    int oc = e & 63;
    const float* ps = accP + (size_t)e * 16;
    const float* pq = accP + 16384 + (size_t)e * 16;
    float s = 0.f, q = 0.f;
#pragma unroll
    for (int i = 0; i < 16; ++i) { s += ps[i]; q += pq[i]; }
    float m = s * (1.f / 16384.f);
    float var = q * (1.f / 16384.f) - m * m;
    float sf = g1[oc] * rsqrtf(var + 1e-5f);
    sc[e] = sf;
    sh[e] = be1[oc] - m * sf;
}

__global__ __launch_bounds__(256) void k_conv1_apply3(
        const float* __restrict__ videos, const float* __restrict__ w1,
        const float* __restrict__ b1, const float* __restrict__ sc,
        const float* __restrict__ sh, float* __restrict__ x1p) {
    __shared__ float sP[3 * 18 * 66];
    __shared__ float wsm[3 * 9 * 16];
    int oc0 = blockIdx.x * 16, rq = blockIdx.y, n = blockIdx.z;
    int c = n >> 2, b = n & 3;
    int tid = threadIdx.x;
    int rp = tid >> 5, cq = tid & 31;
    for (int e = tid; e < 3564; e += 256) {
        int ic = e / 1188, rem = e % 1188;
        int r = rem / 66, col = rem % 66;
        int gr = rq * 16 - 1 + r, gc = col - 1;
        float v = 0.f;
        if (gr >= 0 && gr < 64 && gc >= 0 && gc < 64)
            v = videos[((size_t)(b * 3 + ic) * 32 + 2 * c) * 4096 + gr * 64 + gc];
        sP[e] = v;
    }
    for (int e = tid; e < 432; e += 256) {
        int ic = e / 144, rem = e % 144, k = rem / 16, j = rem % 16;
        wsm[e] = w1[((size_t)((oc0 + j) * 3 + ic) * 3 + 1) * 9 + k];
    }
    __syncthreads();
    float acc[4][16];
#pragma unroll
    for (int p = 0; p < 4; ++p)
#pragma unroll
        for (int j = 0; j < 16; ++j) acc[p][j] = 0.f;
#pragma unroll
    for (int ic = 0; ic < 3; ++ic) {
        const float* base = &sP[ic * 1188 + (2 * rp) * 66 + 2 * cq];
        float patch[4][4];
#pragma unroll
        for (int r = 0; r < 4; ++r)
#pragma unroll
            for (int q = 0; q < 4; ++q) patch[r][q] = base[r * 66 + q];
#pragma unroll
        for (int k = 0; k < 9; ++k) {
            int kr = k / 3, kc = k % 3;
            float4 w0 = *(const float4*)&wsm[(ic * 9 + k) * 16 + 0];
            float4 w1v = *(const float4*)&wsm[(ic * 9 + k) * 16 + 4];
            float4 w2 = *(const float4*)&wsm[(ic * 9 + k) * 16 + 8];
            float4 w3 = *(const float4*)&wsm[(ic * 9 + k) * 16 + 12];
#pragma unroll
            for (int p = 0; p < 4; ++p) {
                float vv = patch[(p >> 1) + kr][(p & 1) + kc];
                acc[p][0]  += vv * w0.x; acc[p][1]  += vv * w0.y;
                acc[p][2]  += vv * w0.z; acc[p][3]  += vv * w0.w;
                acc[p][4]  += vv * w1v.x; acc[p][5]  += vv * w1v.y;
                acc[p][6]  += vv * w1v.z; acc[p][7]  += vv * w1v.w;
                acc[p][8]  += vv * w2.x; acc[p][9]  += vv * w2.y;
                acc[p][10] += vv * w2.z; acc[p][11] += vv * w2.w;
                acc[p][12] += vv * w3.x; acc[p][13] += vv * w3.y;
                acc[p][14] += vv * w3.z; acc[p][15] += vv * w3.w;
            }
        }
    }
#pragma unroll
    for (int j = 0; j < 16; ++j) {
        int oc = oc0 + j;
        float bj = b1[oc];
        float scj = sc[c * 64 + oc], shj = sh[c * 64 + oc];
        float m = -1e30f;
#pragma unroll
        for (int p = 0; p < 4; ++p) m = fmaxf(m, (acc[p][j] + bj) * scj + shj);
        x1p[((size_t)n * 64 + oc) * 1024 + (rq * 8 + rp) * 32 + cq] = fmaxf(m, 0.f);
    }
}

// ============================================================================
// conv2: IC=64, 32x32, OC=128. Block = 32 oc x 8-row slab x 1 clip.
// grid (4 ocg, 4 slab, 64 n) = 1024 blocks. Thread = 4 oc x (2x4 px):
// ocq = tid>>5 (8 quads), rg = (tid>>3)&3 (2 rows), cg = tid&7 (4 cols).
// 288 FMA per 24 patch reads per c-iter. Staging divides in-loop (low VGPR).
// ============================================================================
__global__ __launch_bounds__(256) void k_conv2(
        const float* __restrict__ in, const float* __restrict__ wt,
        const float* __restrict__ bias, float* __restrict__ out) {
    __shared__ float sIn[8 * 10 * 35];   // 2800
    __shared__ float sW[8 * 9 * 32];     // 2304
    int oc0 = blockIdx.x * 32, r0 = blockIdx.y * 8, n = blockIdx.z;
    int tid = threadIdx.x;
    int ocq = tid >> 5;          // 0..7
    int rg = (tid >> 3) & 3;     // rows r0+2rg, r0+2rg+1
    int cg = tid & 7;            // cols 4cg..4cg+3
    float acc[4][8];
#pragma unroll
    for (int j = 0; j < 4; ++j)
#pragma unroll
        for (int p = 0; p < 8; ++p) acc[j][p] = 0.f;

    for (int ic0 = 0; ic0 < 64; ic0 += 8) {
        __syncthreads();
        for (int e = tid; e < 2800; e += 256) {
            int ch = e / 350, rem = e % 350;
            int r = rem / 35, col = rem % 35;
            int gr = r0 - 1 + r, gc = col - 1;
            float v = 0.f;
            if (gr >= 0 && gr < 32 && gc >= 0 && gc < 32)
                v = in[((size_t)(n * 64 + ic0 + ch) * 32 + gr) * 32 + gc];
            sIn[e] = v;
        }
        for (int e = tid; e < 2304; e += 256) {
            int c = e / 288, r1 = e % 288, k = r1 / 32, j = r1 % 32;
            sW[e] = wt[((size_t)(oc0 + j) * 64 + ic0 + c) * 27 + 9 + k];
        }
        __syncthreads();
        for (int c = 0; c < 8; ++c) {
            const float* base = &sIn[c * 350 + (2 * rg) * 35 + 4 * cg];
            float patch[4][6];
#pragma unroll
            for (int r = 0; r < 4; ++r)
#pragma unroll
                for (int q = 0; q < 6; ++q) patch[r][q] = base[r * 35 + q];
#pragma unroll
            for (int k = 0; k < 9; ++k) {
                int kr = k / 3, kc = k % 3;
                float4 w4 = *(const float4*)&sW[c * 288 + k * 32 + ocq * 4];
#pragma unroll
                for (int p = 0; p < 8; ++p) {
                    int pr = p >> 2, pcq = p & 3;
                    float vv = patch[pr + kr][pcq + kc];
                    acc[0][p] += vv * w4.x; acc[1][p] += vv * w4.y;
                    acc[2][p] += vv * w4.z; acc[3][p] += vv * w4.w;
                }
            }
        }
    }
#pragma unroll
    for (int j = 0; j < 4; ++j) {
        int oc = oc0 + ocq * 4 + j;
        float bj = bias[oc];
#pragma unroll
        for (int pr = 0; pr < 2; ++pr) {
            float4 o4 = make_float4(acc[j][pr * 4 + 0] + bj, acc[j][pr * 4 + 1] + bj,
                                    acc[j][pr * 4 + 2] + bj, acc[j][pr * 4 + 3] + bj);
            *(float4*)&out[((size_t)(n * 128 + oc) * 32 + r0 + 2 * rg + pr) * 32 + 4 * cg] = o4;
        }
    }
}

// ============================================================================
// conv3: IC=128, 16x16, OC=256. Block = 32 oc x full plane x 1 clip.
// grid (8 ocg, 64 n) = 512 blocks. Thread = 4 oc x (2x4 px):
// ocq = tid>>5 (8 quads), rg = (tid>>2)&7 (2 rows), cg = tid&3 (4 cols).
// ============================================================================
__global__ __launch_bounds__(256) void k_conv3k(
        const float* __restrict__ in, const float* __restrict__ wt,
        const float* __restrict__ bias, float* __restrict__ out) {
    __shared__ float sIn[8 * 18 * 19];   // 2736
    __shared__ float sW[8 * 9 * 32];     // 2304
    int oc0 = blockIdx.x * 32, n = blockIdx.y;
    int tid = threadIdx.x;
    int ocq = tid >> 5;          // 0..7
    int rg = (tid >> 2) & 7;     // rows 2rg, 2rg+1
    int cg = tid & 3;            // cols 4cg..4cg+3
    float acc[4][8];
#pragma unroll
    for (int j = 0; j < 4; ++j)
#pragma unroll
        for (int p = 0; p < 8; ++p) acc[j][p] = 0.f;

    for (int ic0 = 0; ic0 < 128; ic0 += 8) {
        __syncthreads();
        for (int e = tid; e < 2736; e += 256) {
            int ch = e / 342, rem = e % 342;
            int r = rem / 19, cc = rem % 19;
            int gr = r - 1, gc = cc - 1;
            float v = 0.f;
            if (gr >= 0 && gr < 16 && gc >= 0 && gc < 16)
                v = in[((size_t)(n * 128 + ic0 + ch) * 16 + gr) * 16 + gc];
            sIn[e] = v;
        }
        for (int e = tid; e < 2304; e += 256) {
            int c = e / 288, r1 = e % 288, k = r1 / 32, j = r1 % 32;
            sW[e] = wt[((size_t)(oc0 + j) * 128 + ic0 + c) * 27 + 9 + k];
        }
        __syncthreads();
        for (int c = 0; c < 8; ++c) {
            const float* base = &sIn[c * 342 + (2 * rg) * 19 + 4 * cg];
            float patch[4][6];
#pragma unroll
            for (int r = 0; r < 4; ++r)
#pragma unroll
                for (int q = 0; q < 6; ++q) patch[r][q] = base[r * 19 + q];
#pragma unroll
            for (int k = 0; k < 9; ++k) {
                int kr = k / 3, kc = k % 3;
                float4 w4 = *(const float4*)&sW[c * 288 + k * 32 + ocq * 4];
#pragma unroll
                for (int p = 0; p < 8; ++p) {
                    int pr = p >> 2, pcq = p & 3;
                    float vv = patch[pr + kr][pcq + kc];
                    acc[0][p] += vv * w4.x; acc[1][p] += vv * w4.y;
                    acc[2][p] += vv * w4.z; acc[3][p] += vv * w4.w;
                }
            }
        }
    }
#pragma unroll
    for (int j = 0; j < 4; ++j) {
        int oc = oc0 + ocq * 4 + j;
        float bj = bias[oc];
#pragma unroll
        for (int pr = 0; pr < 2; ++pr) {
            float4 o4 = make_float4(acc[j][pr * 4 + 0] + bj, acc[j][pr * 4 + 1] + bj,
                                    acc[j][pr * 4 + 2] + bj, acc[j][pr * 4 + 3] + bj);
            *(float4*)&out[((size_t)(n * 256 + oc) * 16 + 2 * rg + pr) * 16 + 4 * cg] = o4;
        }
    }
}

// per-(clip,channel) BN stats
__global__ void k_bn_stats(const float* __restrict__ buf, const float* __restrict__ g,
                           const float* __restrict__ be, float* __restrict__ scale,
                           float* __restrict__ shift, int C, int HW) {
    int c = blockIdx.x, ch = blockIdx.y, tid = threadIdx.x;
    float s = 0.f, s2 = 0.f;
    for (int b = 0; b < 4; ++b) {
        const float* p = buf + ((size_t)(c * 4 + b) * C + ch) * HW;
        for (int i = tid; i < HW; i += 256) { float v = p[i]; s += v; s2 += v * v; }
    }
    __shared__ float rs[256], rq[256];
    rs[tid] = s; rq[tid] = s2; __syncthreads();
    for (int k = 128; k > 0; k >>= 1) {
        if (tid < k) { rs[tid] += rs[tid + k]; rq[tid] += rq[tid + k]; }
        __syncthreads();
    }
    if (tid == 0) {
        float inv = 1.f / (float)(4 * HW);
        float m = rs[0] * inv, var = rq[0] * inv - m * m;
        float sc = g[ch] * rsqrtf(var + 1e-5f);
        scale[c * C + ch] = sc;
        shift[c * C + ch] = be[ch] - m * sc;
    }
}

__global__ void k_bn_apply_pool(const float* __restrict__ in, const float* __restrict__ scale,
                                const float* __restrict__ shift, float* __restrict__ out,
                                int C, int H, int W) {
    int OH = H >> 1, OW = W >> 1;
    size_t idx = (size_t)blockIdx.x * 256 + threadIdx.x;
    int ow = (int)(idx % OW);
    size_t r = idx / OW;
    int oh = (int)(r % OH); r /= OH;
    int ch = (int)(r % C);
    int n = (int)(r / C);
    int c = n >> 2;
    float sc = scale[c * C + ch], sh = shift[c * C + ch];
    const float* p = in + (((size_t)n * C + ch) * H + 2 * oh) * W + 2 * ow;
    float m = 0.f;
    m = fmaxf(m, p[0] * sc + sh);
    m = fmaxf(m, p[1] * sc + sh);
    m = fmaxf(m, p[W] * sc + sh);
    m = fmaxf(m, p[W + 1] * sc + sh);
    out[idx] = m;
}

// ---- post-conv3 chain ----
__global__ void k_bn_apply_avgpool4(const float* __restrict__ in, const float* __restrict__ scale,
                                    const float* __restrict__ shift, float* __restrict__ out) {
    size_t idx = (size_t)blockIdx.x * 256 + threadIdx.x;  // 262,144
    int j = (int)(idx & 3), i = (int)(idx >> 2) & 3;
    int ch = (int)(idx >> 4) & 255, n = (int)(idx >> 12);
    int c = n >> 2;
    float sc = scale[c * 256 + ch], sh = shift[c * 256 + ch];
    const float* p = in + (((size_t)n * 256 + ch) * 16 + i * 4) * 16 + j * 4;
    float s = 0.f;
#pragma unroll
    for (int r = 0; r < 4; ++r)
#pragma unroll
        for (int q = 0; q < 4; ++q) s += fmaxf(p[r * 16 + q] * sc + sh, 0.f);
    out[idx] = s * (1.f / 16.f);
}

__global__ void k_tconv(const float* __restrict__ x3p, const float* __restrict__ tw,
                        const float* __restrict__ tb, float* __restrict__ y4) {
    size_t idx = (size_t)blockIdx.x * 256 + threadIdx.x;  // 262,144
    int p = (int)(idx & 15), o = (int)(idx >> 4) & 255, n = (int)(idx >> 12);
    const float* xr = x3p + (size_t)n * 4096 + p;
    float a = tb[o];
    for (int i = 0; i < 256; ++i) a += xr[i * 16] * tw[((size_t)o * 256 + i) * 3 + 1];
    y4[idx] = a;
}

__global__ void k_bn_apply(const float* __restrict__ in, const float* __restrict__ scale,
                           const float* __restrict__ shift, float* __restrict__ out) {
    size_t idx = (size_t)blockIdx.x * 256 + threadIdx.x;  // 262,144
    int ch = (int)(idx >> 4) & 255, n = (int)(idx >> 12);
    int c = n >> 2;
    float sc = scale[c * 256 + ch], sh = shift[c * 256 + ch];
    out[idx] = fmaxf(in[idx] * sc + sh, 0.f);
}

// ============================================================================
// proj as deterministic split-K GEMM with row permutation in fin.
// ============================================================================
__global__ __launch_bounds__(256) void k_proj_part(
        const float* __restrict__ A, const float* __restrict__ B, float* __restrict__ PP) {
    __shared__ __align__(16) float As[64 * 68];
    __shared__ __align__(16) float Bs[64 * 68];
    int n0 = blockIdx.x * 64, ks = blockIdx.y;
    int tid = threadIdx.x, tm = tid >> 4, tn = tid & 15;
    float acc[4][4];
#pragma unroll
    for (int i = 0; i < 4; ++i)
#pragma unroll
        for (int j = 0; j < 4; ++j) acc[i][j] = 0.f;
    int kb = ks * 512;
    for (int k0 = kb; k0 < kb + 512; k0 += 64) {
        __syncthreads();
        for (int e = tid; e < 4096; e += 256) {
            int m = e >> 6, k = e & 63;
            As[k * 68 + m] = A[(size_t)m * 4096 + k0 + k];
            Bs[k * 68 + m] = B[(size_t)(n0 + m) * 4096 + k0 + k];
        }
        __syncthreads();
        for (int k = 0; k < 64; ++k) {
            float4 a4 = *(const float4*)&As[k * 68 + tm * 4];
            float4 b4 = *(const float4*)&Bs[k * 68 + tn * 4];
            acc[0][0] += a4.x * b4.x; acc[0][1] += a4.x * b4.y;
            acc[0][2] += a4.x * b4.z; acc[0][3] += a4.x * b4.w;
            acc[1][0] += a4.y * b4.x; acc[1][1] += a4.y * b4.y;
            acc[1][2] += a4.y * b4.z; acc[1][3] += a4.y * b4.w;
            acc[2][0] += a4.z * b4.x; acc[2][1] += a4.z * b4.y;
            acc[2][2] += a4.z * b4.z; acc[2][3] += a4.z * b4.w;
            acc[3][0] += a4.w * b4.x; acc[3][1] += a4.w * b4.y;
            acc[3][2] += a4.w * b4.z; acc[3][3] += a4.w * b4.w;
        }
    }
#pragma unroll
    for (int i = 0; i < 4; ++i)
#pragma unroll
        for (int j = 0; j < 4; ++j)
            PP[((size_t)(ks * 64 + tm * 4 + i)) * 512 + n0 + tn * 4 + j] = acc[i][j];
}

__global__ void k_proj_fin(const float* __restrict__ PP, const float* __restrict__ pb,
                           float* __restrict__ feat) {
    int e = blockIdx.x * 256 + threadIdx.x;  // 32768
    int n = e & 511;
    int m = e >> 9;               // x4 row (clip-major): m = c*4 + b
    float s = pb[n];
#pragma unroll
    for (int ks = 0; ks < 8; ++ks) s += PP[(size_t)ks * 32768 + e];
    int c = m >> 2, b = m & 3;
    int ro = b * 16 + c;          // feat row (batch-major)
    feat[(size_t)ro * 512 + n] = s;
}

// VQ argmin; min distance -> commitArr[row] (deterministic)
__global__ void k_vq(const float* __restrict__ feat, const float* __restrict__ cb,
                     float* __restrict__ quant, float* __restrict__ commitArr) {
    int row = blockIdx.x, tid = threadIdx.x;
    __shared__ float f[512];
    for (int k = tid; k < 512; k += 256) f[k] = feat[(size_t)row * 512 + k];
    __syncthreads();
    float best = 3.4e38f; int bidx = 0;
    for (int j = tid; j < 1024; j += 256) {
        const float* c = cb + (size_t)j * 512;
        float d2 = 0.f;
        for (int k = 0; k < 512; ++k) { float t = f[k] - c[k]; d2 += t * t; }
        if (d2 < best) { best = d2; bidx = j; }
    }
    __shared__ float rd[256]; __shared__ int ri[256];
    rd[tid] = best; ri[tid] = bidx; __syncthreads();
    for (int k = 128; k > 0; k >>= 1) {
        if (tid < k) {
            float od = rd[tid + k]; int oi = ri[tid + k];
            if (od < rd[tid] || (od == rd[tid] && oi < ri[tid])) { rd[tid] = od; ri[tid] = oi; }
        }
        __syncthreads();
    }
    __shared__ int wsel;
    if (tid == 0) { wsel = ri[0]; commitArr[row] = rd[0]; }
    __syncthreads();
    const float* c = cb + (size_t)wsel * 512;
    for (int k = tid; k < 512; k += 256) quant[(size_t)row * 512 + k] = c[k];
}

// gi = X @ w_ih.T + b_ih, rows (b, t) t=0..14; rows at stride-16 (b*16+t)
__global__ void k_gru_gi(const float* __restrict__ x, const float* __restrict__ wih,
                         const float* __restrict__ bih, float* __restrict__ gi) {
    int r = blockIdx.x;  // 0..59
    int b = r / 15, t = r % 15;
    const float* xr = x + ((size_t)(b * 16 + t)) * 512;
    __shared__ float xsRow[512];
    for (int k = threadIdx.x; k < 512; k += 256) xsRow[k] = xr[k];
    __syncthreads();
    const float4* xp = (const float4*)xsRow;
    for (int d = threadIdx.x; d < 1536; d += 256) {
        const float4* wr = (const float4*)(wih + (size_t)d * 512);
        float a0 = 0.f, a1 = 0.f, a2 = 0.f, a3 = 0.f;
        for (int i = 0; i < 128; i += 4) {
            float4 w0 = wr[i], w1 = wr[i + 1], w2 = wr[i + 2], w3 = wr[i + 3];
            float4 x0 = xp[i], x1 = xp[i + 1], x2 = xp[i + 2], x3 = xp[i + 3];
            a0 += w0.x * x0.x + w0.y * x0.y + w0.z * x0.z + w0.w * x0.w;
            a1 += w1.x * x1.x + w1.y * x1.y + w1.z * x1.z + w1.w * x1.w;
            a2 += w2.x * x2.x + w2.y * x2.y + w2.z * x2.z + w2.w * x2.w;
            a3 += w3.x * x3.x + w3.y * x3.y + w3.z * x3.z + w3.w * x3.w;
        }
        gi[((size_t)(b * 16 + t)) * 1536 + d] = (a0 + a1) + (a2 + a3) + bih[d];
    }
}

// One GRU step: grid 128 (4 h-dims each), wave = one h-dim, float4 rows.
__global__ void k_gru_step2(const float* __restrict__ gi, const float* __restrict__ whh,
                            const float* __restrict__ bhh, float* __restrict__ hseq, int t) {
    int wv = threadIdx.x >> 6, lane = threadIdx.x & 63;
    int d = blockIdx.x * 4 + wv;
    const float4* w0p = (const float4*)(whh + (size_t)d * 512);
    const float4* w1p = (const float4*)(whh + (size_t)(512 + d) * 512);
    const float4* w2p = (const float4*)(whh + (size_t)(1024 + d) * 512);
    float4 w0a = w0p[lane * 2], w0b = w0p[lane * 2 + 1];
    float4 w1a = w1p[lane * 2], w1b = w1p[lane * 2 + 1];
    float4 w2a = w2p[lane * 2], w2b = w2p[lane * 2 + 1];
    float bh0 = bhh[d], bh1 = bhh[512 + d], bh2 = bhh[1024 + d];
    for (int b = 0; b < 4; ++b) {
        float4 ha = make_float4(0, 0, 0, 0), hb = ha;
        float hpd = 0.f;
        if (t > 0) {
            const float4* hp = (const float4*)(hseq + (size_t)(b * 16 + t - 1) * 512);
            ha = hp[lane * 2]; hb = hp[lane * 2 + 1];
            hpd = hseq[(size_t)(b * 16 + t - 1) * 512 + d];
        }
        float s0 = w0a.x * ha.x + w0a.y * ha.y + w0a.z * ha.z + w0a.w * ha.w
                 + w0b.x * hb.x + w0b.y * hb.y + w0b.z * hb.z + w0b.w * hb.w;
        float s1 = w1a.x * ha.x + w1a.y * ha.y + w1a.z * ha.z + w1a.w * ha.w
                 + w1b.x * hb.x + w1b.y * hb.y + w1b.z * hb.z + w1b.w * hb.w;
        float s2 = w2a.x * ha.x + w2a.y * ha.y + w2a.z * ha.z + w2a.w * ha.w
                 + w2b.x * hb.x + w2b.y * hb.y + w2b.z * hb.z + w2b.w * hb.w;
#pragma unroll
        for (int m = 1; m < 64; m <<= 1) {
            s0 += __shfl_xor(s0, m);
            s1 += __shfl_xor(s1, m);
            s2 += __shfl_xor(s2, m);
        }
        const float* gr = gi + (size_t)(b * 16 + t) * 1536;
        float rr = 1.f / (1.f + expf(-(gr[d] + s0 + bh0)));
        float zz = 1.f / (1.f + expf(-(gr[512 + d] + s1 + bh1)));
        float nn = tanhf(gr[1024 + d] + rr * (s2 + bh2));
        if (lane == 0)
            hseq[(size_t)(b * 16 + t) * 512 + d] = (1.f - zz) * nn + zz * hpd;
    }
}

// ctx loss partials -> ctxArr[block] (deterministic)
__global__ void k_ctx_loss(const float* __restrict__ h2, const float* __restrict__ feat,
                           float* __restrict__ ctxArr) {
    int tid = threadIdx.x;
    size_t idx = (size_t)blockIdx.x * 256 + tid;  // 30720
    int d = (int)(idx & 511);
    int rt = (int)(idx >> 9);
    int t = rt % 15, b = rt / 15;
    float diff = h2[(size_t)(b * 16 + t) * 512 + d] - feat[(size_t)(b * 16 + t + 1) * 512 + d];
    float v = diff * diff;
#pragma unroll
    for (int m = 1; m < 64; m <<= 1) v += __shfl_xor(v, m);
    __shared__ float ws[4];
    if ((tid & 63) == 0) ws[tid >> 6] = v;
    __syncthreads();
    if (tid == 0) ctxArr[blockIdx.x] = ((ws[0] + ws[1]) + (ws[2] + ws[3]));
}

__global__ void k_word_vq(const float* __restrict__ quant, const float* __restrict__ wcb,
                          float* __restrict__ wemb, float* __restrict__ out_widx) {
    int row = blockIdx.x;  // b*8+wi
    int b = row >> 3, wi = row & 7;
    int tid = threadIdx.x;
    __shared__ float f[512];
    for (int k = tid; k < 512; k += 256)
        f[k] = 0.5f * (quant[(size_t)(b * 16 + 2 * wi) * 512 + k] +
                       quant[(size_t)(b * 16 + 2 * wi + 1) * 512 + k]);
    __syncthreads();
    const float* cp = wcb + (size_t)tid * 512;
    float d2 = 0.f;
    for (int k = 0; k < 512; ++k) { float t = f[k] - cp[k]; d2 += t * t; }
    __shared__ float rd[256]; __shared__ int ri[256];
    rd[tid] = d2; ri[tid] = tid; __syncthreads();
    for (int k = 128; k > 0; k >>= 1) {
        if (tid < k) {
            float od = rd[tid + k]; int oi = ri[tid + k];
            if (od < rd[tid] || (od == rd[tid] && oi < ri[tid])) { rd[tid] = od; ri[tid] = oi; }
        }
        __syncthreads();
    }
    __shared__ int wsel;
    if (tid == 0) { wsel = ri[0]; out_widx[row] = (float)ri[0]; }
    __syncthreads();
    const float* cb = wcb + (size_t)wsel * 512;
    for (int k = tid; k < 512; k += 256) wemb[(size_t)row * 512 + k] = cb[k];
}

// alignment partials -> alignArr[row] (deterministic)
__global__ void k_align(const float* __restrict__ wemb, const float* __restrict__ aw,
                        const float* __restrict__ ab, float* __restrict__ alignArr) {
    int row = blockIdx.x, tid = threadIdx.x;
    __shared__ float e[512];
    for (int k = tid; k < 512; k += 256) e[k] = wemb[(size_t)row * 512 + k];
    __syncthreads();
    float local = 0.f;
    for (int d = tid; d < 512; d += 256) {
        const float* wr = aw + (size_t)d * 512;
        float a = ab[d] - e[d];
        for (int k = 0; k < 512; ++k) a += e[k] * wr[k];
        local += a * a;
    }
    __shared__ float rs[256];
    rs[tid] = local; __syncthreads();
    for (int k = 128; k > 0; k >>= 1) { if (tid < k) rs[tid] += rs[tid + k]; __syncthreads(); }
    if (tid == 0) alignArr[row] = rs[0];
}

__global__ void k_ctx(const float* __restrict__ wemb, float* __restrict__ ctx) {
    int e = blockIdx.x * 256 + threadIdx.x;  // 2048
    int b = e >> 9, d = e & 511;
    float s = 0.f;
#pragma unroll
    for (int wi = 0; wi < 8; ++wi) s += wemb[(size_t)(b * 8 + wi) * 512 + d];
    ctx[e] = s * 0.125f;
}

// small-M (M=4) GEMV: C[4,N] = A[4,K] @ B[N,K]^T + bias, optional relu.
__global__ void k_smallM(const float* __restrict__ A, const float* __restrict__ B,
                         const float* __restrict__ bias, float* __restrict__ C,
                         int N, int K, int relu) {
    __shared__ float xs[4096];
    int tid = threadIdx.x;
    for (int e = tid; e < 4 * K; e += 256) xs[e] = A[e];
    __syncthreads();
    int r = tid >> 4, kt = tid & 15;
    int n = blockIdx.x * 16 + r;
    float acc[4] = {0, 0, 0, 0};
    if (n < N) {
        int iters = K >> 6;
        for (int i = 0; i < iters; ++i) {
            int k = i * 64 + kt * 4;
            float4 w = *(const float4*)&B[(size_t)n * K + k];
#pragma unroll
            for (int b = 0; b < 4; ++b) {
                float4 x = *(const float4*)&xs[b * K + k];
                acc[b] += w.x * x.x + w.y * x.y + w.z * x.z + w.w * x.w;
            }
        }
    }
#pragma unroll
    for (int b = 0; b < 4; ++b) {
#pragma unroll
        for (int m = 1; m < 16; m <<= 1) acc[b] += __shfl_xor(acc[b], m);
    }
    if (kt == 0 && n < N) {
#pragma unroll
        for (int b = 0; b < 4; ++b) {
            float v = acc[b] + bias[n];
            if (relu) v = fmaxf(v, 0.f);
            C[(size_t)b * N + n] = v;
        }
    }
}

// log-softmax CE + deterministic fixed-order sum of all loss partials
__global__ void k_final(const float* __restrict__ logits, const int* __restrict__ tokens,
                        const float* __restrict__ commitArr, const float* __restrict__ ctxArr,
                        const float* __restrict__ alignArr, float* __restrict__ out_total) {
    int tid = threadIdx.x;
    __shared__ float rs[256];
    __shared__ float sM;
    float tr = 0.f;
    for (int b = 0; b < 4; ++b) {
        const float* lg = logits + (size_t)b * 3000;
        float m = -1e30f;
        for (int d = tid; d < 3000; d += 256) m = fmaxf(m, lg[d]);
        rs[tid] = m; __syncthreads();
        for (int k = 128; k > 0; k >>= 1) { if (tid < k) rs[tid] = fmaxf(rs[tid], rs[tid + k]); __syncthreads(); }
        if (tid == 0) sM = rs[0];
        __syncthreads();
        float M = sM;
        float s = 0.f;
        for (int d = tid; d < 3000; d += 256) s += expf(lg[d] - M);
        rs[tid] = s; __syncthreads();
        for (int k = 128; k > 0; k >>= 1) { if (tid < k) rs[tid] += rs[tid + k]; __syncthreads(); }
        if (tid == 0) {
            int t0 = tokens[b * 10];
            tr += -(lg[t0] - M - logf(rs[0]));
        }
        __syncthreads();
    }
    if (tid == 0) {
        float c0 = 0.f;
        for (int i = 0; i < 64; ++i) c0 += commitArr[i];
        float c1 = 0.f;
        for (int i = 0; i < 120; ++i) c1 += ctxArr[i];
        float c2 = 0.f;
        for (int i = 0; i < 32; ++i) c2 += alignArr[i];
        float total = 1.25f * c0 * (1.f / 32768.f)
                    + 0.1f  * c1 * (1.f / 30720.f)
                    + 0.1f  * c2 * (1.f / 16384.f)
                    + tr;
        *out_total = total;
    }
}

extern "C" void kernel_launch(void* const* d_in, const int* in_sizes, int n_in,
                              void* d_out, int out_size, void* d_ws, size_t ws_size,
                              hipStream_t stream) {
    (void)in_sizes; (void)n_in; (void)out_size; (void)ws_size;
    const float* videos   = (const float*)d_in[0];
    const float* conv1_w  = (const float*)d_in[1];
    const float* conv1_b  = (const float*)d_in[2];
    const float* bn1_g    = (const float*)d_in[3];
    const float* bn1_b    = (const float*)d_in[4];
    const float* conv2_w  = (const float*)d_in[5];
    const float* conv2_b  = (const float*)d_in[6];
    const float* bn2_g    = (const float*)d_in[7];
    const float* bn2_b    = (const float*)d_in[8];
    const float* conv3_w  = (const float*)d_in[9];
    const float* conv3_b  = (const float*)d_in[10];
    const float* bn3_g    = (const float*)d_in[11];
    const float* bn3_b    = (const float*)d_in[12];
    const float* tconv_w  = (const float*)d_in[13];
    const float* tconv_b  = (const float*)d_in[14];
    const float* bn4_g    = (const float*)d_in[15];
    const float* bn4_b    = (const float*)d_in[16];
    const float* proj_w   = (const float*)d_in[17];
    const float* proj_b   = (const float*)d_in[18];
    const float* codebook = (const float*)d_in[19];
    const float* word_cb  = (const float*)d_in[20];
    const float* align_w  = (const float*)d_in[21];
    const float* align_b  = (const float*)d_in[22];
    const float* gru_wih0 = (const float*)d_in[23];
    const float* gru_whh0 = (const float*)d_in[24];
    const float* gru_bih0 = (const float*)d_in[25];
    const float* gru_bhh0 = (const float*)d_in[26];
    const float* gru_wih1 = (const float*)d_in[27];
    const float* gru_whh1 = (const float*)d_in[28];
    const float* gru_bih1 = (const float*)d_in[29];
    const float* gru_bhh1 = (const float*)d_in[30];
    const float* dec1_w   = (const float*)d_in[31];
    const float* dec1_b   = (const float*)d_in[32];
    const float* dec2_w   = (const float*)d_in[33];
    const float* dec2_b   = (const float*)d_in[34];
    const float* dec3_w   = (const float*)d_in[35];
    const float* dec3_b   = (const float*)d_in[36];
    const int*   tokens   = (const int*)d_in[37];

    float* wsf    = (float*)d_ws;
    float* out    = (float*)d_out;
    float* x1p    = wsf + OFF_X1P;
    float* x2p    = wsf + OFF_X2P;
    float* y2     = wsf + OFF_Y2;
    float* y3     = wsf + OFF_Y3;
    float* x3p    = wsf + OFF_X3P;
    float* y4     = wsf + OFF_Y4;
    float* x4     = wsf + OFF_X4;
    float* feat   = wsf + OFF_FEAT;
    float* quant  = wsf + OFF_QUANT;
    float* gi1    = wsf + OFF_GI1;
    float* gi2    = wsf + OFF_GI2;
    float* h1     = wsf + OFF_H1;
    float* h2     = wsf + OFF_H2;
    float* wemb   = wsf + OFF_WEMB;
    float* ctx    = wsf + OFF_CTX;
    float* hh1    = wsf + OFF_HH1;
    float* hh2    = wsf + OFF_HH2;
    float* logit  = wsf + OFF_LOG;
    float* pp     = wsf + OFF_PP;
    float* sc     = wsf + OFF_SC;
    float* sh     = wsf + OFF_SH;
    float* accP   = wsf + OFF_ACCP;
    float* commitA= wsf + OFF_COMMIT;
    float* ctxA   = wsf + OFF_CTXA;
    float* alignA = wsf + OFF_ALIGNA;

    // conv1 + bn1 + pool
    k_conv1_stats3<<<dim3(4, 4, 64), 256, 0, stream>>>(videos, conv1_w, conv1_b, accP);
    k_conv1_fin<<<4, 256, 0, stream>>>(accP, bn1_g, bn1_b, sc, sh);
    k_conv1_apply3<<<dim3(4, 4, 64), 256, 0, stream>>>(videos, conv1_w, conv1_b, sc, sh, x1p);
    // conv2 + bn2 + pool
    k_conv2<<<dim3(4, 4, 64), 256, 0, stream>>>(x1p, conv2_w, conv2_b, y2);
    k_bn_stats<<<dim3(16, 128), 256, 0, stream>>>(y2, bn2_g, bn2_b, sc, sh, 128, 1024);
    k_bn_apply_pool<<<8192, 256, 0, stream>>>(y2, sc, sh, x2p, 128, 32, 32);
    // conv3 + bn3 + chain
    k_conv3k<<<dim3(8, 64), 256, 0, stream>>>(x2p, conv3_w, conv3_b, y3);
    k_bn_stats<<<dim3(16, 256), 256, 0, stream>>>(y3, bn3_g, bn3_b, sc, sh, 256, 256);
    k_bn_apply_avgpool4<<<1024, 256, 0, stream>>>(y3, sc, sh, x3p);
    k_tconv<<<1024, 256, 0, stream>>>(x3p, tconv_w, tconv_b, y4);
    k_bn_stats<<<dim3(16, 256), 256, 0, stream>>>(y4, bn4_g, bn4_b, sc, sh, 256, 16);
    k_bn_apply<<<1024, 256, 0, stream>>>(y4, sc, sh, x4);
    // projection (deterministic split-K GEMM, row permutation in fin)
    k_proj_part<<<dim3(8, 8), 256, 0, stream>>>(x4, proj_w, pp);
    k_proj_fin<<<128, 256, 0, stream>>>(pp, proj_b, feat);
    k_vq<<<64, 256, 0, stream>>>(feat, codebook, quant, commitA);
    // GRU layer 1
    k_gru_gi<<<60, 256, 0, stream>>>(quant, gru_wih0, gru_bih0, gi1);
    for (int t = 0; t < 15; ++t)
        k_gru_step2<<<128, 256, 0, stream>>>(gi1, gru_whh0, gru_bhh0, h1, t);
    // GRU layer 2
    k_gru_gi<<<60, 256, 0, stream>>>(h1, gru_wih1, gru_bih1, gi2);
    for (int t = 0; t < 15; ++t)
        k_gru_step2<<<128, 256, 0, stream>>>(gi2, gru_whh1, gru_bhh1, h2, t);
    k_ctx_loss<<<120, 256, 0, stream>>>(h2, feat, ctxA);
    // word VQ + alignment
    k_word_vq<<<32, 256, 0, stream>>>(quant, word_cb, wemb, out);
    k_align<<<32, 256, 0, stream>>>(wemb, align_w, align_b, alignA);
    // decoder
    k_ctx<<<8, 256, 0, stream>>>(wemb, ctx);
    k_smallM<<<32, 256, 0, stream>>>(ctx, dec1_w, dec1_b, hh1, 512, 512, 1);
    k_smallM<<<64, 256, 0, stream>>>(hh1, dec2_w, dec2_b, hh2, 1024, 512, 1);
    k_smallM<<<188, 256, 0, stream>>>(hh2, dec3_w, dec3_b, logit, 3000, 1024, 0);
    k_final<<<1, 256, 0, stream>>>(logit, tokens, commitA, ctxA, alignA, out + 32);
}